// Round 1
// baseline (553.787 us; speedup 1.0000x reference)
//
#include <hip/hip_runtime.h>
#include <stdint.h>

// ---------------------------------------------------------------------------
// LDAM: pooled dual-modality non-local attention + BN + residual + 2x upsample
// B=8, C=256, IC=128, H=W=128 -> pooled 64x64 (Nq=4096), sub-sampled 32x32
// (Nkv=1024). Score path (theta/phi conv + Q.K^T) in split-bf16 (hi+lo) for
// ~fp32 accuracy through the softmax; value path plain bf16.
// ---------------------------------------------------------------------------

typedef unsigned short u16;
typedef short bf16x8 __attribute__((ext_vector_type(8)));
typedef float f32x4 __attribute__((ext_vector_type(4)));

#define MFMA16(a, b, c) __builtin_amdgcn_mfma_f32_16x16x32_bf16(a, b, c, 0, 0, 0)

__device__ __forceinline__ u16 f2bf(float x) {
    union { float f; unsigned int u; } v; v.f = x;
    unsigned int u = v.u;
    unsigned int r = u + 0x7fffu + ((u >> 16) & 1u);   // round-nearest-even
    return (u16)(r >> 16);
}
__device__ __forceinline__ float bf2f(u16 h) {
    union { unsigned int u; float f; } v; v.u = ((unsigned int)h) << 16;
    return v.f;
}

// ---------------------------------------------------------------------------
// K0: zero the BN accumulator region (ws is poisoned 0xAA before every call)
// ---------------------------------------------------------------------------
__global__ void zero_kernel(float* __restrict__ p, int n) {
    int i = blockIdx.x * 256 + threadIdx.x;
    if (i < n) p[i] = 0.0f;
}

// ---------------------------------------------------------------------------
// K1: 2x2 maxpool + NCHW -> [pos, c] transpose + hi/lo bf16 split.
// grid = B*64*4 (b, h2 row, 64-channel tile); block = 256.
// ---------------------------------------------------------------------------
__global__ __launch_bounds__(256) void pool_transpose_kernel(
    const float* __restrict__ x, u16* __restrict__ ohi, u16* __restrict__ olo) {
    __shared__ float tile[64][65];  // [w2][c_local], +1 pad
    int bx = blockIdx.x;
    int ct = bx & 3, h2 = (bx >> 2) & 63, b = bx >> 8;
    int tid = threadIdx.x;
    int col = tid & 127;        // raw column 0..127
    int chalf = tid >> 7;       // which of 2 channels this pass

    long base_in = (((long)b * 256 + ct * 64) * 128 + 2 * h2) * 128;
#pragma unroll 4
    for (int i = 0; i < 32; i++) {
        int c_l = i * 2 + chalf;
        const float* p = x + base_in + (long)c_l * 16384;
        float m = fmaxf(p[col], p[128 + col]);          // vertical max
        float o = __shfl_xor(m, 1);                     // horizontal partner
        m = fmaxf(m, o);
        if ((col & 1) == 0) tile[col >> 1][c_l] = m;
    }
    __syncthreads();
    long obase = ((long)b * 4096 + h2 * 64) * 256 + ct * 64;
#pragma unroll 4
    for (int i = 0; i < 16; i++) {
        int idx = i * 256 + tid;
        int w2 = idx >> 6, c_l = idx & 63;
        float v = tile[w2][c_l];
        u16 h = f2bf(v);
        long oi = obase + (long)w2 * 256 + c_l;
        ohi[oi] = h;
        olo[oi] = f2bf(v - bf2f(h));
    }
}

// ---------------------------------------------------------------------------
// K2: split all four weight matrices (each 32768 elems) into bf16 hi/lo planes
// plane layout (ushort units): mat m in {theta,phi,g,W}: hi at m*65536, lo +32768
// ---------------------------------------------------------------------------
__global__ void wsplit_kernel(const float* __restrict__ tw, const float* __restrict__ pw,
                              const float* __restrict__ gw, const float* __restrict__ ww,
                              u16* __restrict__ planes) {
    int idx = blockIdx.x * 256 + threadIdx.x;   // 512*256 = 131072 = 4*32768
    int m = idx >> 15, e = idx & 32767;
    const float* src = (m == 0) ? tw : (m == 1) ? pw : (m == 2) ? gw : ww;
    float v = src[e];
    u16 h = f2bf(v);
    planes[m * 65536 + e] = h;
    planes[m * 65536 + 32768 + e] = f2bf(v - bf2f(h));
}

// ---------------------------------------------------------------------------
// K3: generic 1x1 conv as GEMM  out[M, O] = A[M, K] * W[O, K]^T + bias.
// A-frags loaded directly from global (64B-granule coalesced across quads);
// weight k-chunk staged in LDS per iteration. SPLIT => 3-product split-bf16.
// OMODE: 0 = bf16 out, 1 = bf16 hi+lo out, 2 = fp32 out.
// grid = M/64, block = 256 (4 waves x 16 rows).
// ---------------------------------------------------------------------------
template <int K, int O, bool SPLIT, int OMODE>
__global__ __launch_bounds__(256) void conv1x1_kernel(
    const u16* __restrict__ Ahi, const u16* __restrict__ Alo,
    const u16* __restrict__ Whi, const u16* __restrict__ Wlo,
    const float* __restrict__ bias,
    u16* __restrict__ out_hi, u16* __restrict__ out_lo, float* __restrict__ out_f) {
    constexpr int NT = O / 16;
    __shared__ u16 Wh[O * 40];                    // [O][32] + 8 pad per row
    __shared__ u16 Wl[SPLIT ? O * 40 : 8];

    int tid = threadIdx.x;
    int wave = tid >> 6, lane = tid & 63, quad = lane >> 4, l16 = lane & 15;
    long mbase = (long)blockIdx.x * 64;

    f32x4 acc[NT];
#pragma unroll
    for (int nt = 0; nt < NT; nt++)
#pragma unroll
        for (int r = 0; r < 4; r++) acc[nt][r] = 0.0f;

    for (int k0 = 0; k0 < K; k0 += 32) {
        __syncthreads();
        // stage weight tile [O][32] (hi and, if SPLIT, lo)
#pragma unroll
        for (int p = 0; p < O * 4; p += 256) {
            int cid = p + tid;
            int o = cid >> 2, koff = (cid & 3) * 8;
            *(uint4*)&Wh[o * 40 + koff] = *(const uint4*)&Whi[(long)o * K + k0 + koff];
            if (SPLIT)
                *(uint4*)&Wl[o * 40 + koff] = *(const uint4*)&Wlo[(long)o * K + k0 + koff];
        }
        __syncthreads();

        long arow = mbase + wave * 16 + l16;
        bf16x8 ah = *(const bf16x8*)&Ahi[arow * K + k0 + quad * 8];
        bf16x8 al;
        if (SPLIT) al = *(const bf16x8*)&Alo[arow * K + k0 + quad * 8];

#pragma unroll
        for (int nt = 0; nt < NT; nt++) {
            bf16x8 bh = *(const bf16x8*)&Wh[(nt * 16 + l16) * 40 + quad * 8];
            acc[nt] = MFMA16(ah, bh, acc[nt]);
            if (SPLIT) {
                bf16x8 bl = *(const bf16x8*)&Wl[(nt * 16 + l16) * 40 + quad * 8];
                acc[nt] = MFMA16(ah, bl, acc[nt]);
                acc[nt] = MFMA16(al, bh, acc[nt]);
            }
        }
    }

    // epilogue: + bias, store per C/D layout (col = l16 tile, row = quad*4+r)
#pragma unroll
    for (int nt = 0; nt < NT; nt++) {
        int colo = nt * 16 + l16;
        float bv = bias[colo];
#pragma unroll
        for (int r = 0; r < 4; r++) {
            long row = mbase + wave * 16 + quad * 4 + r;
            float v = acc[nt][r] + bv;
            long idx = row * O + colo;
            if (OMODE == 2) {
                out_f[idx] = v;
            } else if (OMODE == 0) {
                out_hi[idx] = f2bf(v);
            } else {
                u16 h = f2bf(v);
                out_hi[idx] = h;
                out_lo[idx] = f2bf(v - bf2f(h));
            }
        }
    }
}

// ---------------------------------------------------------------------------
// K4: sub-sample pool phi: [B,4096,128] hi/lo -> K layout [B,1024,128] hi/lo
// ---------------------------------------------------------------------------
__global__ __launch_bounds__(256) void pool_phiK_kernel(
    const u16* __restrict__ fhi, const u16* __restrict__ flo,
    u16* __restrict__ khi, u16* __restrict__ klo) {
    long idx = (long)blockIdx.x * 256 + threadIdx.x;  // 8*1024*128 total
    int c = idx & 127;
    long r = idx >> 7;
    int kv = (int)(r & 1023), b = (int)(r >> 10);
    int h4 = kv >> 5, w4 = kv & 31;
    long p00 = ((long)b * 4096 + (2 * h4) * 64 + 2 * w4) * 128 + c;
    float v = -3.0e38f;
#pragma unroll
    for (int rr = 0; rr < 2; rr++)
#pragma unroll
        for (int ss = 0; ss < 2; ss++) {
            long p = p00 + rr * 8192 + ss * 128;
            float f = bf2f(fhi[p]) + bf2f(flo[p]);
            v = fmaxf(v, f);
        }
    u16 h = f2bf(v);
    khi[idx] = h;
    klo[idx] = f2bf(v - bf2f(h));
}

// ---------------------------------------------------------------------------
// K5: sub-sample pool g + transpose: [B,4096,128] bf16 -> V^T [B,128,1024]
// grid = 8*16*2 (b, 64-kv tile, 64-c tile)
// ---------------------------------------------------------------------------
__global__ __launch_bounds__(256) void pool_gVt_kernel(
    const u16* __restrict__ g, u16* __restrict__ vt) {
    __shared__ u16 t[64][65];   // [c_l][kv_l]
    int bx = blockIdx.x;
    int ct = bx & 1, kvt = (bx >> 1) & 15, b = bx >> 5;
    int tid = threadIdx.x;
#pragma unroll 4
    for (int i = 0; i < 16; i++) {
        int idx = i * 256 + tid;
        int kv_l = idx >> 6, c_l = idx & 63;
        int kv = kvt * 64 + kv_l;
        int h4 = kv >> 5, w4 = kv & 31;
        long p00 = ((long)b * 4096 + (2 * h4) * 64 + 2 * w4) * 128 + ct * 64 + c_l;
        float v = fmaxf(fmaxf(bf2f(g[p00]), bf2f(g[p00 + 128])),
                        fmaxf(bf2f(g[p00 + 8192]), bf2f(g[p00 + 8192 + 128])));
        t[c_l][kv_l] = f2bf(v);
    }
    __syncthreads();
    long ob = ((long)b * 128 + ct * 64) * 1024 + kvt * 64;
#pragma unroll 4
    for (int i = 0; i < 16; i++) {
        int idx = i * 256 + tid;
        int c_l = idx >> 6, kv_l = idx & 63;
        vt[ob + (long)c_l * 1024 + kv_l] = t[c_l][kv_l];
    }
}

// ---------------------------------------------------------------------------
// K6: fused flash attention. Q tile 64 rows/block (16/wave), KV tile 64,
// online softmax, scores in split-bf16 (3 MFMA), PV plain. P routed through
// per-wave LDS to convert C-layout -> A-layout (m120-verified pattern).
// grid = 512 (b = bx&7 for XCD L2 locality, qt = bx>>3), block = 256.
// ---------------------------------------------------------------------------
__global__ __launch_bounds__(256) void attn_kernel(
    const u16* __restrict__ th, const u16* __restrict__ tl,
    const u16* __restrict__ khi, const u16* __restrict__ klo,
    const u16* __restrict__ vt, u16* __restrict__ y) {
    __shared__ u16 Kh[64][136];    // [kv][c] hi, rows 16B aligned, 2-way banks
    __shared__ u16 Kl[64][136];    // [kv][c] lo
    __shared__ u16 Vt[128][72];    // [c][kv]
    __shared__ u16 Pl[4][16][72];  // per-wave P tile [qrow][kv]

    int bx = blockIdx.x;
    int b = bx & 7, qt = bx >> 3;
    int tid = threadIdx.x;
    int w = tid >> 6, lane = tid & 63, quad = lane >> 4, l16 = lane & 15;
    int qbase = qt * 64 + w * 16;

    // Q fragments (hi+lo), reused for all KV tiles
    bf16x8 qh[4], ql[4];
    long tb = ((long)b * 4096 + qbase + l16) * 128;
#pragma unroll
    for (int kc = 0; kc < 4; kc++) {
        qh[kc] = *(const bf16x8*)&th[tb + kc * 32 + quad * 8];
        ql[kc] = *(const bf16x8*)&tl[tb + kc * 32 + quad * 8];
    }

    f32x4 o[8];
#pragma unroll
    for (int t2 = 0; t2 < 8; t2++)
#pragma unroll
        for (int r = 0; r < 4; r++) o[t2][r] = 0.0f;
    float m[4] = {-1e30f, -1e30f, -1e30f, -1e30f};
    float l[4] = {0.0f, 0.0f, 0.0f, 0.0f};

#pragma unroll 1
    for (int it = 0; it < 16; it++) {
        int kv0 = it * 64;
        __syncthreads();   // protect LDS reuse from previous iteration's reads
        // stage K hi/lo: 64 rows x 128 c (1024 16B chunks per plane)
#pragma unroll
        for (int p = 0; p < 1024; p += 256) {
            int cid = p + tid;
            int row = cid >> 4, ko = (cid & 15) * 8;
            long src = ((long)b * 1024 + kv0 + row) * 128 + ko;
            *(uint4*)&Kh[row][ko] = *(const uint4*)&khi[src];
            *(uint4*)&Kl[row][ko] = *(const uint4*)&klo[src];
        }
        // stage V^T: 128 rows x 64 kv
#pragma unroll
        for (int p = 0; p < 1024; p += 256) {
            int cid = p + tid;
            int row = cid >> 3, ko = (cid & 7) * 8;
            long src = ((long)b * 128 + row) * 1024 + kv0 + ko;
            *(uint4*)&Vt[row][ko] = *(const uint4*)&vt[src];
        }
        __syncthreads();

        // S = Q.K^T (split: QhKh + QhKl + QlKh), 16x64 per wave
        f32x4 s[4];
#pragma unroll
        for (int nt = 0; nt < 4; nt++)
#pragma unroll
            for (int r = 0; r < 4; r++) s[nt][r] = 0.0f;
#pragma unroll
        for (int kc = 0; kc < 4; kc++) {
#pragma unroll
            for (int nt = 0; nt < 4; nt++) {
                bf16x8 bh = *(const bf16x8*)&Kh[nt * 16 + l16][kc * 32 + quad * 8];
                bf16x8 bl = *(const bf16x8*)&Kl[nt * 16 + l16][kc * 32 + quad * 8];
                s[nt] = MFMA16(qh[kc], bh, s[nt]);
                s[nt] = MFMA16(qh[kc], bl, s[nt]);
                s[nt] = MFMA16(ql[kc], bh, s[nt]);
            }
        }

        // online softmax per row (row = quad*4 + r, cols across l16 x 4 tiles)
        float pv[4][4];
#pragma unroll
        for (int r = 0; r < 4; r++) {
            float rm = fmaxf(fmaxf(s[0][r], s[1][r]), fmaxf(s[2][r], s[3][r]));
#pragma unroll
            for (int off = 1; off < 16; off <<= 1) rm = fmaxf(rm, __shfl_xor(rm, off));
            float mn = fmaxf(m[r], rm);
            float al = __expf(m[r] - mn);
            m[r] = mn;
            float rs = 0.0f;
#pragma unroll
            for (int nt = 0; nt < 4; nt++) {
                float p = __expf(s[nt][r] - mn);
                pv[nt][r] = p;
                rs += p;
            }
#pragma unroll
            for (int off = 1; off < 16; off <<= 1) rs += __shfl_xor(rs, off);
            l[r] = l[r] * al + rs;
#pragma unroll
            for (int t2 = 0; t2 < 8; t2++) o[t2][r] *= al;
        }

        // P: C-layout -> LDS -> A-layout (same-wave write/read, wave-ordered)
#pragma unroll
        for (int nt = 0; nt < 4; nt++)
#pragma unroll
            for (int r = 0; r < 4; r++)
                Pl[w][quad * 4 + r][nt * 16 + l16] = f2bf(pv[nt][r]);

        // O += P.V
#pragma unroll
        for (int kc2 = 0; kc2 < 2; kc2++) {
            bf16x8 pa = *(const bf16x8*)&Pl[w][l16][kc2 * 32 + quad * 8];
#pragma unroll
            for (int t2 = 0; t2 < 8; t2++) {
                bf16x8 vb = *(const bf16x8*)&Vt[t2 * 16 + l16][kc2 * 32 + quad * 8];
                o[t2] = MFMA16(pa, vb, o[t2]);
            }
        }
    }

    // epilogue: normalize and store y[B,4096,128] bf16
#pragma unroll
    for (int r = 0; r < 4; r++) {
        float inv = 1.0f / l[r];
        long row = (long)b * 4096 + qbase + quad * 4 + r;
#pragma unroll
        for (int t2 = 0; t2 < 8; t2++)
            y[row * 128 + t2 * 16 + l16] = f2bf(o[t2][r] * inv);
    }
}

// ---------------------------------------------------------------------------
// K7: BN statistics: per-channel sum & sumsq over Wy [32768, 256]
// ---------------------------------------------------------------------------
__global__ __launch_bounds__(256) void bnstat_kernel(const float* __restrict__ wy,
                                                     float* __restrict__ acc) {
    int c = threadIdx.x;
    long r0 = (long)blockIdx.x * 128;
    float s = 0.0f, q = 0.0f;
#pragma unroll 4
    for (int i = 0; i < 128; i++) {
        float v = wy[(r0 + i) * 256 + c];
        s += v;
        q += v * v;
    }
    atomicAdd(&acc[c], s);
    atomicAdd(&acc[256 + c], q);
}

// ---------------------------------------------------------------------------
// K8: BN normalize + residual + 2x nearest upsample to NCHW fp32 output.
// grid = B*64*4 (b, h2, 16-w2 tile); block = 256.
// ---------------------------------------------------------------------------
__global__ __launch_bounds__(256) void final_kernel(
    const float* __restrict__ wy, const u16* __restrict__ rgbhi,
    const float* __restrict__ acc, const float* __restrict__ gamma,
    const float* __restrict__ beta, float* __restrict__ out) {
    __shared__ float z[16][257];
    int bx = blockIdx.x;
    int wt = bx & 3, h2 = (bx >> 2) & 63, b = bx >> 8;
    int c = threadIdx.x;

    float mean = acc[c] * (1.0f / 32768.0f);
    float var = acc[256 + c] * (1.0f / 32768.0f) - mean * mean;
    float rstd = rsqrtf(var + 1e-5f);
    float gm = gamma[c] * rstd;
    float bt = beta[c] - mean * gm;

    long pbase = (long)b * 4096 + h2 * 64 + wt * 16;
#pragma unroll 4
    for (int i = 0; i < 16; i++) {
        long pi = (pbase + i) * 256 + c;
        z[i][c] = wy[pi] * gm + bt + bf2f(rgbhi[pi]);
    }
    __syncthreads();
    int tid = threadIdx.x;
#pragma unroll 4
    for (int pass = 0; pass < 64; pass++) {
        int cc = pass * 4 + (tid >> 6);
        int r = (tid >> 5) & 1, wc = tid & 31;
        float v = z[wc >> 1][cc];
        out[(((long)b * 256 + cc) * 128 + 2 * h2 + r) * 128 + wt * 32 + wc] = v;
    }
}

// ---------------------------------------------------------------------------
// Launch: workspace layout (bytes), total ~115.9 MB with aliasing:
//   rgbpt_hi   0          (16.78M)  live to end
//   rgbpt_lo   16777216   (16.78M)  dead after theta conv  } Wy aliases
//   evpt_hi    33554432   (16.78M)  dead after g conv      } these 33.55M
//   evpt_lo    50331648   (16.78M)  dead after phi conv
//   theta_hi   67108864   (8.39M)
//   theta_lo   75497472   (8.39M)
//   phiF_hi    83886080   (8.39M)   dead after pool_phiK -> y aliases
//   phiF_lo    92274688   (8.39M)
//   g_full     100663296  (8.39M)
//   phiK_hi    109051904  (2.10M)
//   phiK_lo    111149056  (2.10M)
//   gVt        113246208  (2.10M)
//   wplanes    115343360  (512K)
//   bn acc     115867648  (2K)
// ---------------------------------------------------------------------------
extern "C" void kernel_launch(void* const* d_in, const int* in_sizes, int n_in,
                              void* d_out, int out_size, void* d_ws, size_t ws_size,
                              hipStream_t stream) {
    const float* rgb     = (const float*)d_in[0];
    const float* event_  = (const float*)d_in[1];
    const float* g_w     = (const float*)d_in[2];
    const float* g_b     = (const float*)d_in[3];
    const float* theta_w = (const float*)d_in[4];
    const float* theta_b = (const float*)d_in[5];
    const float* phi_w   = (const float*)d_in[6];
    const float* phi_b   = (const float*)d_in[7];
    const float* W_w     = (const float*)d_in[8];
    const float* W_b     = (const float*)d_in[9];
    const float* gamma   = (const float*)d_in[10];
    const float* beta    = (const float*)d_in[11];

    char* ws = (char*)d_ws;
    u16* rgbpt_hi = (u16*)(ws + 0);
    u16* rgbpt_lo = (u16*)(ws + 16777216);
    u16* evpt_hi  = (u16*)(ws + 33554432);
    u16* evpt_lo  = (u16*)(ws + 50331648);
    u16* theta_hi = (u16*)(ws + 67108864);
    u16* theta_lo = (u16*)(ws + 75497472);
    u16* phiF_hi  = (u16*)(ws + 83886080);
    u16* phiF_lo  = (u16*)(ws + 92274688);
    u16* g_full   = (u16*)(ws + 100663296);
    u16* phiK_hi  = (u16*)(ws + 109051904);
    u16* phiK_lo  = (u16*)(ws + 111149056);
    u16* gVt      = (u16*)(ws + 113246208);
    u16* y        = phiF_hi;                      // alias (phiF dead by then)
    float* Wy     = (float*)(ws + 16777216);      // alias rgbpt_lo + evpt_hi
    u16* wplanes  = (u16*)(ws + 115343360);
    float* acc    = (float*)(ws + 115867648);

    zero_kernel<<<2, 256, 0, stream>>>(acc, 512);
    pool_transpose_kernel<<<2048, 256, 0, stream>>>(rgb, rgbpt_hi, rgbpt_lo);
    pool_transpose_kernel<<<2048, 256, 0, stream>>>(event_, evpt_hi, evpt_lo);
    wsplit_kernel<<<512, 256, 0, stream>>>(theta_w, phi_w, g_w, W_w, wplanes);

    // theta = conv(rgb_p) split-precision, out hi/lo
    conv1x1_kernel<256, 128, true, 1><<<512, 256, 0, stream>>>(
        rgbpt_hi, rgbpt_lo, wplanes + 0, wplanes + 32768, theta_b,
        theta_hi, theta_lo, nullptr);
    // phi = conv(ev_p) split-precision, out hi/lo (full res, pooled next)
    conv1x1_kernel<256, 128, true, 1><<<512, 256, 0, stream>>>(
        evpt_hi, evpt_lo, wplanes + 65536, wplanes + 98304, phi_b,
        phiF_hi, phiF_lo, nullptr);
    // g = conv(ev_p) plain bf16
    conv1x1_kernel<256, 128, false, 0><<<512, 256, 0, stream>>>(
        evpt_hi, nullptr, wplanes + 131072, nullptr, g_b,
        g_full, nullptr, nullptr);

    pool_phiK_kernel<<<4096, 256, 0, stream>>>(phiF_hi, phiF_lo, phiK_hi, phiK_lo);
    pool_gVt_kernel<<<256, 256, 0, stream>>>(g_full, gVt);

    attn_kernel<<<512, 256, 0, stream>>>(theta_hi, theta_lo, phiK_hi, phiK_lo, gVt, y);

    // W_y = conv(y), fp32 out [B*4096, 256]
    conv1x1_kernel<128, 256, false, 2><<<512, 256, 0, stream>>>(
        y, nullptr, wplanes + 196608, nullptr, W_b, nullptr, nullptr, Wy);

    bnstat_kernel<<<256, 256, 0, stream>>>(Wy, acc);
    final_kernel<<<2048, 256, 0, stream>>>(Wy, rgbpt_hi, acc, gamma, beta, (float*)d_out);
}